// Round 2
// baseline (532.345 us; speedup 1.0000x reference)
//
#include <hip/hip_runtime.h>
#include <stdint.h>

#define NAT 65536
#define CH 512
#define NQKV 768

typedef __bf16 bf16x8 __attribute__((ext_vector_type(8)));
typedef float f32x4 __attribute__((ext_vector_type(4)));

union B8 { uint4 u; __bf16 h[8]; };

__device__ __forceinline__ void gload16(const void* g, void* l) {
  __builtin_amdgcn_global_load_lds((const __attribute__((address_space(1))) void*)g,
                                   (__attribute__((address_space(3))) void*)l, 16, 0, 0);
}

// ---------------- prep: fp32 -> bf16 conversions + stats zero ----------------
__global__ void k_prep(const float* __restrict__ atom, const float* __restrict__ wqk,
                       const float* __restrict__ bqk, const float* __restrict__ wv,
                       const float* __restrict__ bv, const float* __restrict__ wt,
                       __bf16* __restrict__ atom16, __bf16* __restrict__ wqkv16,
                       float* __restrict__ bqkv, __bf16* __restrict__ wt16,
                       float* __restrict__ stats)
{
  int tid = blockIdx.x * blockDim.x + threadIdx.x;
  int nth = gridDim.x * blockDim.x;
  const float4* a4 = (const float4*)atom;
  for (int i = tid; i < NAT * CH / 8; i += nth) {
    float4 x = a4[2 * i], y = a4[2 * i + 1];
    B8 u;
    u.h[0] = (__bf16)x.x; u.h[1] = (__bf16)x.y; u.h[2] = (__bf16)x.z; u.h[3] = (__bf16)x.w;
    u.h[4] = (__bf16)y.x; u.h[5] = (__bf16)y.y; u.h[6] = (__bf16)y.z; u.h[7] = (__bf16)y.w;
    ((uint4*)atom16)[i] = u.u;
  }
  for (int i = tid; i < NQKV * CH / 8; i += nth) {
    int row = (i * 8) >> 9;
    const float* src = (row < 256) ? (wqk + (size_t)i * 8) : (wv + (size_t)i * 8 - 256 * 512);
    float4 x = ((const float4*)src)[0], y = ((const float4*)src)[1];
    B8 u;
    u.h[0] = (__bf16)x.x; u.h[1] = (__bf16)x.y; u.h[2] = (__bf16)x.z; u.h[3] = (__bf16)x.w;
    u.h[4] = (__bf16)y.x; u.h[5] = (__bf16)y.y; u.h[6] = (__bf16)y.z; u.h[7] = (__bf16)y.w;
    ((uint4*)wqkv16)[i] = u.u;
  }
  for (int i = tid; i < CH * CH / 8; i += nth) {
    float4 x = ((const float4*)wt)[2 * i], y = ((const float4*)wt)[2 * i + 1];
    B8 u;
    u.h[0] = (__bf16)x.x; u.h[1] = (__bf16)x.y; u.h[2] = (__bf16)x.z; u.h[3] = (__bf16)x.w;
    u.h[4] = (__bf16)y.x; u.h[5] = (__bf16)y.y; u.h[6] = (__bf16)y.z; u.h[7] = (__bf16)y.w;
    ((uint4*)wt16)[i] = u.u;
  }
  if (tid < NQKV) bqkv[tid] = (tid < 256) ? bqk[tid] : bv[tid - 256];
  if (tid < 1024) stats[tid] = 0.f;
}

// ---------------- GEMM: C[M,NOUT] = A[M,512] @ W[NOUT,512]^T + bias ----------------
// 128x128 tile, BK=64, 4 waves (2x2 of 64x64), mfma 16x16x32 bf16.
// LDS linear (global_load_lds), XOR slot-swizzle applied on the GLOBAL source and on reads.
template<int NOUT, bool STATS>
__global__ __launch_bounds__(256, 2) void k_gemm(const __bf16* __restrict__ A,
    const __bf16* __restrict__ W, const float* __restrict__ bias,
    __bf16* __restrict__ Cout, float* __restrict__ stats)
{
  __shared__ __align__(16) char lds[32768];   // A tile 16KB + B tile 16KB
  const int t = threadIdx.x, w = t >> 6, l = t & 63;
  const int wr = w >> 1, wc = w & 1;
  const int m0 = blockIdx.x * 128, n0 = blockIdx.y * 128;
  const int lsub = l >> 3;                 // 0..7
  const int lslot = (l & 7) ^ lsub;        // pre-swizzled global 16B-slot
  f32x4 acc[4][4] = {};

  for (int kt = 0; kt < 8; ++kt) {
    const int k0 = kt * 64;
#pragma unroll
    for (int i = 0; i < 4; ++i) {
      int row = (w * 4 + i) * 8 + lsub;    // 0..127, per-wave slice
      gload16(A + ((size_t)(m0 + row) * 512 + k0 + lslot * 8), lds + (w * 4 + i) * 1024);
      gload16(W + ((size_t)(n0 + row) * 512 + k0 + lslot * 8), lds + 16384 + (w * 4 + i) * 1024);
    }
    asm volatile("s_waitcnt vmcnt(0)" ::: "memory");
    __syncthreads();
#pragma unroll
    for (int ks = 0; ks < 2; ++ks) {
      bf16x8 af[4], bfr[4];
#pragma unroll
      for (int mi = 0; mi < 4; ++mi) {
        int r = wr * 64 + mi * 16 + (l & 15);
        int slot = (ks * 4 + (l >> 4)) ^ (r & 7);
        af[mi] = *(const bf16x8*)(lds + r * 128 + (slot << 4));
      }
#pragma unroll
      for (int ni = 0; ni < 4; ++ni) {
        int r = wc * 64 + ni * 16 + (l & 15);
        int slot = (ks * 4 + (l >> 4)) ^ (r & 7);
        bfr[ni] = *(const bf16x8*)(lds + 16384 + r * 128 + (slot << 4));
      }
#pragma unroll
      for (int mi = 0; mi < 4; ++mi)
#pragma unroll
        for (int ni = 0; ni < 4; ++ni)
          acc[mi][ni] = __builtin_amdgcn_mfma_f32_16x16x32_bf16(af[mi], bfr[ni], acc[mi][ni], 0, 0, 0);
    }
    __syncthreads();
  }

  float ssum[4] = {0, 0, 0, 0}, ssq[4] = {0, 0, 0, 0};
#pragma unroll
  for (int ni = 0; ni < 4; ++ni) {
    int col = n0 + wc * 64 + ni * 16 + (l & 15);
    float bb = bias[col];
#pragma unroll
    for (int mi = 0; mi < 4; ++mi) {
#pragma unroll
      for (int r = 0; r < 4; ++r) {
        int row = m0 + wr * 64 + mi * 16 + (l >> 4) * 4 + r;
        float v = acc[mi][ni][r] + bb;
        Cout[(size_t)row * NOUT + col] = (__bf16)v;
        if (STATS) { ssum[ni] += v; ssq[ni] += v * v; }
      }
    }
  }
  if (STATS) {
#pragma unroll
    for (int ni = 0; ni < 4; ++ni) {
      float s = ssum[ni], q = ssq[ni];
      s += __shfl_xor(s, 16, 64); q += __shfl_xor(q, 16, 64);
      s += __shfl_xor(s, 32, 64); q += __shfl_xor(q, 32, 64);
      if (l < 16) {
        int col = n0 + wc * 64 + ni * 16 + l;
        atomicAdd(&stats[col], s);
        atomicAdd(&stats[512 + col], q);
      }
    }
  }
}

// ---------------- per-crystal attention ----------------
// One block per crystal (64 atoms). energy = qk qk^T / 16 ; softmax over query axis i ;
// L1 over key axis j ; x_r = att @ v ; xt = atom - x_r (bf16 out).
__global__ __launch_bounds__(256, 2) void k_attn(const __bf16* __restrict__ qkv,
    const float* __restrict__ atom, __bf16* __restrict__ xt)
{
  __shared__ __align__(16) char sm[49920];
  // region0 [0,32768): qk [64][256] bf16 swz, later reused for v_t half [256][64] bf16 swz
  float* E = (float*)(sm + 32768);         // [64][65] f32 (padded)
  float* colinv = (float*)(sm + 49408);    // [64]
  float* rowinv = (float*)(sm + 49664);    // [64]
  const int t = threadIdx.x, w = t >> 6, l = t & 63;
  const size_t g0 = (size_t)blockIdx.x * 64;

  // stage qk [64][256], XOR-swizzled 16B slots
#pragma unroll
  for (int i = 0; i < 8; ++i) {
    int chunk = i * 256 + t;
    int row = chunk >> 5, slot = chunk & 31;
    uint4 d = *(const uint4*)(qkv + (g0 + row) * NQKV + slot * 8);
    *(uint4*)(sm + row * 512 + ((slot ^ (row & 7)) << 4)) = d;
  }
  __syncthreads();

  // energy: wave w computes rows [16w, 16w+16)
  f32x4 eacc[4] = {};
#pragma unroll
  for (int kk = 0; kk < 8; ++kk) {
    int ra = 16 * w + (l & 15);
    bf16x8 af = *(const bf16x8*)(sm + ra * 512 + (((kk * 4 + (l >> 4)) ^ (ra & 7)) << 4));
#pragma unroll
    for (int nj = 0; nj < 4; ++nj) {
      int rb = 16 * nj + (l & 15);
      bf16x8 bf_ = *(const bf16x8*)(sm + rb * 512 + (((kk * 4 + (l >> 4)) ^ (rb & 7)) << 4));
      eacc[nj] = __builtin_amdgcn_mfma_f32_16x16x32_bf16(af, bf_, eacc[nj], 0, 0, 0);
    }
  }
#pragma unroll
  for (int nj = 0; nj < 4; ++nj)
#pragma unroll
    for (int r = 0; r < 4; ++r) {
      int i = 16 * w + (l >> 4) * 4 + r;
      int j = 16 * nj + (l & 15);
      E[i * 65 + j] = eacc[nj][r] * 0.0625f;   // / sqrt(dk)=16
    }
  __syncthreads();

  // stage v_t half: v_t[c][j] swizzled; lane l holds row j=l, sweeps channels
  auto stage_v = [&](int h) {
#pragma unroll
    for (int ch = 0; ch < 8; ++ch) {
      int cb = w * 64 + ch * 8;   // channel base within half
      B8 d; d.u = *(const uint4*)(qkv + (g0 + l) * NQKV + 256 + h * 256 + cb);
#pragma unroll
      for (int e = 0; e < 8; ++e) {
        int c = cb + e;
        *(__bf16*)(sm + c * 128 + (((l >> 3) ^ (c & 7)) << 4) + (l & 7) * 2) = d.h[e];
      }
    }
  };

  auto pv_half = [&](int h) {
    f32x4 acc[4][4] = {};
#pragma unroll
    for (int ks = 0; ks < 2; ++ks) {
      bf16x8 af[4];
#pragma unroll
      for (int mi = 0; mi < 4; ++mi) {
        int i = mi * 16 + (l & 15);
        float ri = rowinv[i];
        bf16x8 a;
#pragma unroll
        for (int e = 0; e < 8; ++e) {
          int j = ks * 32 + (l >> 4) * 8 + e;
          a[e] = (__bf16)(E[i * 65 + j] * colinv[j] * ri);
        }
        af[mi] = a;
      }
#pragma unroll
      for (int nc = 0; nc < 4; ++nc) {
        int c = w * 64 + nc * 16 + (l & 15);
        int slot = (ks * 4 + (l >> 4)) ^ (c & 7);
        bf16x8 bfr = *(const bf16x8*)(sm + c * 128 + (slot << 4));
#pragma unroll
        for (int mi = 0; mi < 4; ++mi)
          acc[mi][nc] = __builtin_amdgcn_mfma_f32_16x16x32_bf16(af[mi], bfr, acc[mi][nc], 0, 0, 0);
      }
    }
#pragma unroll
    for (int mi = 0; mi < 4; ++mi)
#pragma unroll
      for (int nc = 0; nc < 4; ++nc)
#pragma unroll
        for (int r = 0; r < 4; ++r) {
          int i = mi * 16 + (l >> 4) * 4 + r;
          int c = h * 256 + w * 64 + nc * 16 + (l & 15);
          size_t idx = (g0 + i) * CH + c;
          xt[idx] = (__bf16)(atom[idx] - acc[mi][nc][r]);
        }
  };

  // overlap v half0 staging with column softmax
  stage_v(0);
  if (t < 64) {          // softmax over i for column j=t
    float m = -1e30f;
    for (int i = 0; i < 64; ++i) m = fmaxf(m, E[i * 65 + t]);
    float s = 0.f;
    for (int i = 0; i < 64; ++i) { float e = __expf(E[i * 65 + t] - m); E[i * 65 + t] = e; s += e; }
    colinv[t] = 1.f / s;
  }
  __syncthreads();
  if (t < 64) {          // L1 over j for row i=t
    float rs = 0.f;
    for (int j = 0; j < 64; ++j) rs += E[t * 65 + j] * colinv[j];
    rowinv[t] = 1.f / (1e-9f + rs);
  }
  __syncthreads();
  pv_half(0);
  __syncthreads();
  stage_v(1);
  __syncthreads();
  pv_half(1);
}

// ---------------- BN scale/shift from accumulated stats ----------------
__global__ void k_stats(const float* __restrict__ stats, const float* __restrict__ gamma,
                        const float* __restrict__ beta, float* __restrict__ ss)
{
  int c = threadIdx.x;
  float mean = stats[c] * (1.f / NAT);
  float var = stats[512 + c] * (1.f / NAT) - mean * mean;
  float sc = gamma[c] * rsqrtf(var + 1e-5f);
  ss[c] = sc;
  ss[512 + c] = beta[c] - mean * sc;
}

// ---------------- final: out = atom + relu(t*scale + shift) ----------------
__global__ void k_final(const float* __restrict__ atom, const __bf16* __restrict__ tmat,
                        const float* __restrict__ ss, float* __restrict__ out)
{
  int tid = blockIdx.x * blockDim.x + threadIdx.x;
  int nth = gridDim.x * blockDim.x;
  for (int i = tid; i < NAT * CH / 8; i += nth) {
    int colb = (i & 63) * 8;
    B8 tv; tv.u = ((const uint4*)tmat)[i];
    float4 a0 = ((const float4*)atom)[2 * i], a1 = ((const float4*)atom)[2 * i + 1];
    float4 s0 = *(const float4*)(ss + colb), s1 = *(const float4*)(ss + colb + 4);
    float4 h0 = *(const float4*)(ss + 512 + colb), h1 = *(const float4*)(ss + 512 + colb + 4);
    float4 o0, o1;
    o0.x = a0.x + fmaxf(0.f, (float)tv.h[0] * s0.x + h0.x);
    o0.y = a0.y + fmaxf(0.f, (float)tv.h[1] * s0.y + h0.y);
    o0.z = a0.z + fmaxf(0.f, (float)tv.h[2] * s0.z + h0.z);
    o0.w = a0.w + fmaxf(0.f, (float)tv.h[3] * s0.w + h0.w);
    o1.x = a1.x + fmaxf(0.f, (float)tv.h[4] * s1.x + h1.x);
    o1.y = a1.y + fmaxf(0.f, (float)tv.h[5] * s1.y + h1.y);
    o1.z = a1.z + fmaxf(0.f, (float)tv.h[6] * s1.z + h1.z);
    o1.w = a1.w + fmaxf(0.f, (float)tv.h[7] * s1.w + h1.w);
    ((float4*)out)[2 * i] = o0;
    ((float4*)out)[2 * i + 1] = o1;
  }
}

extern "C" void kernel_launch(void* const* d_in, const int* in_sizes, int n_in,
                              void* d_out, int out_size, void* d_ws, size_t ws_size,
                              hipStream_t stream) {
  const float* atom  = (const float*)d_in[0];
  const float* wqk   = (const float*)d_in[1];
  const float* bqk   = (const float*)d_in[2];
  const float* wv    = (const float*)d_in[3];
  const float* bv    = (const float*)d_in[4];
  const float* wt    = (const float*)d_in[5];
  const float* bt    = (const float*)d_in[6];
  const float* gamma = (const float*)d_in[7];
  const float* beta  = (const float*)d_in[8];
  char* ws = (char*)d_ws;

  // Region A [0, 64MB): atom16 (dead after QKV GEMM) -> xtr
  // Region B [64MB, 160MB): qkv (dead after attn) -> tmat
  __bf16* atom16 = (__bf16*)(ws);                    // 67,108,864 B
  __bf16* xtr    = (__bf16*)(ws);                    // overlaps atom16 (dead)
  __bf16* qkv    = (__bf16*)(ws + 67108864);         // 100,663,296 B
  __bf16* tmat   = (__bf16*)(ws + 67108864);         // overlaps qkv (dead)
  __bf16* wqkv16 = (__bf16*)(ws + 167772160);        // 786,432 B
  __bf16* wt16   = (__bf16*)(ws + 168558592);        // 524,288 B
  float*  bqkv   = (float*)(ws + 169082880);         // 3,072 B
  float*  stats  = (float*)(ws + 169085952);         // 4,096 B
  float*  ss     = (float*)(ws + 169090048);         // 4,096 B
  float*  out    = (float*)d_out;

  k_prep<<<dim3(2048), dim3(256), 0, stream>>>(atom, wqk, bqk, wv, bv, wt,
                                               atom16, wqkv16, bqkv, wt16, stats);
  k_gemm<NQKV, false><<<dim3(512, 6), dim3(256), 0, stream>>>(atom16, wqkv16, bqkv, qkv, nullptr);
  k_attn<<<dim3(1024), dim3(256), 0, stream>>>(qkv, atom, xtr);
  k_gemm<CH, true><<<dim3(512, 4), dim3(256), 0, stream>>>(xtr, wt16, bt, tmat, stats);
  k_stats<<<dim3(1), dim3(512), 0, stream>>>(stats, gamma, beta, ss);
  k_final<<<dim3(2048), dim3(256), 0, stream>>>(atom, tmat, ss, out);
}

// Round 3
// 529.538 us; speedup vs baseline: 1.0053x; 1.0053x over previous
//
#include <hip/hip_runtime.h>
#include <stdint.h>

#define NAT 65536
#define CH 512
#define NQKV 768

typedef __bf16 bf16x8 __attribute__((ext_vector_type(8)));
typedef float f32x4 __attribute__((ext_vector_type(4)));

union B8 { uint4 u; __bf16 h[8]; };

__device__ __forceinline__ void gload16(const void* g, void* l) {
  __builtin_amdgcn_global_load_lds((const __attribute__((address_space(1))) void*)g,
                                   (__attribute__((address_space(3))) void*)l, 16, 0, 0);
}

// ---------------- prep: fp32 -> bf16 conversions + stats zero ----------------
__global__ void k_prep(const float* __restrict__ atom, const float* __restrict__ wqk,
                       const float* __restrict__ bqk, const float* __restrict__ wv,
                       const float* __restrict__ bv, const float* __restrict__ wt,
                       __bf16* __restrict__ atom16, __bf16* __restrict__ wqkv16,
                       float* __restrict__ bqkv, __bf16* __restrict__ wt16,
                       float* __restrict__ stats)
{
  int tid = blockIdx.x * blockDim.x + threadIdx.x;
  int nth = gridDim.x * blockDim.x;
  const float4* a4 = (const float4*)atom;
  for (int i = tid; i < NAT * CH / 8; i += nth) {
    float4 x = a4[2 * i], y = a4[2 * i + 1];
    B8 u;
    u.h[0] = (__bf16)x.x; u.h[1] = (__bf16)x.y; u.h[2] = (__bf16)x.z; u.h[3] = (__bf16)x.w;
    u.h[4] = (__bf16)y.x; u.h[5] = (__bf16)y.y; u.h[6] = (__bf16)y.z; u.h[7] = (__bf16)y.w;
    ((uint4*)atom16)[i] = u.u;
  }
  for (int i = tid; i < NQKV * CH / 8; i += nth) {
    int row = (i * 8) >> 9;
    const float* src = (row < 256) ? (wqk + (size_t)i * 8) : (wv + (size_t)i * 8 - 256 * 512);
    float4 x = ((const float4*)src)[0], y = ((const float4*)src)[1];
    B8 u;
    u.h[0] = (__bf16)x.x; u.h[1] = (__bf16)x.y; u.h[2] = (__bf16)x.z; u.h[3] = (__bf16)x.w;
    u.h[4] = (__bf16)y.x; u.h[5] = (__bf16)y.y; u.h[6] = (__bf16)y.z; u.h[7] = (__bf16)y.w;
    ((uint4*)wqkv16)[i] = u.u;
  }
  for (int i = tid; i < CH * CH / 8; i += nth) {
    float4 x = ((const float4*)wt)[2 * i], y = ((const float4*)wt)[2 * i + 1];
    B8 u;
    u.h[0] = (__bf16)x.x; u.h[1] = (__bf16)x.y; u.h[2] = (__bf16)x.z; u.h[3] = (__bf16)x.w;
    u.h[4] = (__bf16)y.x; u.h[5] = (__bf16)y.y; u.h[6] = (__bf16)y.z; u.h[7] = (__bf16)y.w;
    ((uint4*)wt16)[i] = u.u;
  }
  if (tid < NQKV) bqkv[tid] = (tid < 256) ? bqk[tid] : bv[tid - 256];
  if (tid < 1024) stats[tid] = 0.f;
}

// ---------------- GEMM: C[M,NOUT] = A[M,512] @ W[NOUT,512]^T + bias ----------------
// 128x128 tile, BK=64, 4 waves (2x2 of 64x64), mfma 16x16x32 bf16.
// 2-phase double-buffered LDS (T3-min), counted vmcnt(8) across raw s_barriers.
// LDS C-stage epilogue for coalesced 16B stores.
template<int NOUT, bool STATS>
__global__ __launch_bounds__(256, 2) void k_gemm(const __bf16* __restrict__ A,
    const __bf16* __restrict__ W, const float* __restrict__ bias,
    __bf16* __restrict__ Cout, float* __restrict__ stats)
{
  __shared__ __align__(16) char lds[65536];   // 2 x (A 16KB + B 16KB)
  const int t = threadIdx.x, w = t >> 6, l = t & 63;
  const int wr = w >> 1, wc = w & 1;
  const int m0 = blockIdx.x * 128, n0 = blockIdx.y * 128;
  const int lsub = l >> 3;                 // 0..7
  const int lslot = (l & 7) ^ lsub;        // pre-swizzled global 16B-slot
  f32x4 acc[4][4] = {};

  auto stage = [&](int kt, int p) {
    const int k0 = kt * 64;
    char* base = lds + p * 32768;
#pragma unroll
    for (int i = 0; i < 4; ++i) {
      int row = (w * 4 + i) * 8 + lsub;    // 0..127, per-wave slice
      gload16(A + ((size_t)(m0 + row) * 512 + k0 + lslot * 8), base + (w * 4 + i) * 1024);
      gload16(W + ((size_t)(n0 + row) * 512 + k0 + lslot * 8), base + 16384 + (w * 4 + i) * 1024);
    }
  };

  stage(0, 0);
#pragma unroll
  for (int kt = 0; kt < 8; ++kt) {
    const int p = kt & 1;
    if (kt < 7) {
      stage(kt + 1, p ^ 1);
      asm volatile("s_waitcnt vmcnt(8)" ::: "memory");   // oldest 8 (buf p) done
    } else {
      asm volatile("s_waitcnt vmcnt(0)" ::: "memory");
    }
    __builtin_amdgcn_s_barrier();
    __builtin_amdgcn_sched_barrier(0);
    const char* base = lds + p * 32768;
#pragma unroll
    for (int ks = 0; ks < 2; ++ks) {
      bf16x8 af[4], bfr[4];
#pragma unroll
      for (int mi = 0; mi < 4; ++mi) {
        int r = wr * 64 + mi * 16 + (l & 15);
        int slot = (ks * 4 + (l >> 4)) ^ (r & 7);
        af[mi] = *(const bf16x8*)(base + r * 128 + (slot << 4));
      }
#pragma unroll
      for (int ni = 0; ni < 4; ++ni) {
        int r = wc * 64 + ni * 16 + (l & 15);
        int slot = (ks * 4 + (l >> 4)) ^ (r & 7);
        bfr[ni] = *(const bf16x8*)(base + 16384 + r * 128 + (slot << 4));
      }
#pragma unroll
      for (int mi = 0; mi < 4; ++mi)
#pragma unroll
        for (int ni = 0; ni < 4; ++ni)
          acc[mi][ni] = __builtin_amdgcn_mfma_f32_16x16x32_bf16(af[mi], bfr[ni], acc[mi][ni], 0, 0, 0);
    }
    if (kt < 7) {
      asm volatile("s_waitcnt lgkmcnt(0)" ::: "memory");  // this wave's reads of buf p done
      __builtin_amdgcn_s_barrier();                       // before buf p is re-staged at kt+2
    }
  }

  // epilogue: bias (+stats), stage C tile to LDS (swizzled), coalesced 16B stores
  float bb[4];
#pragma unroll
  for (int ni = 0; ni < 4; ++ni) bb[ni] = bias[n0 + wc * 64 + ni * 16 + (l & 15)];
  float ssum[4] = {0, 0, 0, 0}, ssq[4] = {0, 0, 0, 0};
#pragma unroll
  for (int ni = 0; ni < 4; ++ni) {
#pragma unroll
    for (int mi = 0; mi < 4; ++mi) {
#pragma unroll
      for (int r = 0; r < 4; ++r) {
        int row = wr * 64 + mi * 16 + (l >> 4) * 4 + r;   // tile-local
        int col = wc * 64 + ni * 16 + (l & 15);
        float v = acc[mi][ni][r] + bb[ni];
        if (STATS) { ssum[ni] += v; ssq[ni] += v * v; }
        int s = col >> 3;
        *(__bf16*)(lds + row * 256 + ((s ^ ((row >> 2) & 15)) << 4) + (col & 7) * 2) = (__bf16)v;
      }
    }
  }
  __syncthreads();
#pragma unroll
  for (int j = 0; j < 8; ++j) {
    int chunk = j * 256 + t;
    int row = chunk >> 4, sp = chunk & 15;
    uint4 d = *(const uint4*)(lds + row * 256 + ((sp ^ ((row >> 2) & 15)) << 4));
    *(uint4*)(Cout + (size_t)(m0 + row) * NOUT + n0 + sp * 8) = d;
  }
  if (STATS) {
#pragma unroll
    for (int ni = 0; ni < 4; ++ni) {
      float s = ssum[ni], q = ssq[ni];
      s += __shfl_xor(s, 16, 64); q += __shfl_xor(q, 16, 64);
      s += __shfl_xor(s, 32, 64); q += __shfl_xor(q, 32, 64);
      if (l < 16) {
        int col = n0 + wc * 64 + ni * 16 + l;
        atomicAdd(&stats[col], s);
        atomicAdd(&stats[512 + col], q);
      }
    }
  }
}

// ---------------- per-crystal attention ----------------
__global__ __launch_bounds__(256, 2) void k_attn(const __bf16* __restrict__ qkv,
    const __bf16* __restrict__ atom16, __bf16* __restrict__ xt)
{
  __shared__ __align__(16) char sm[49920];
  float* E = (float*)(sm + 32768);         // [64][65] f32 (padded)
  float* colinv = (float*)(sm + 49408);    // [64]
  float* rowinv = (float*)(sm + 49664);    // [64]
  const int t = threadIdx.x, w = t >> 6, l = t & 63;
  const size_t g0 = (size_t)blockIdx.x * 64;

#pragma unroll
  for (int i = 0; i < 8; ++i) {
    int chunk = i * 256 + t;
    int row = chunk >> 5, slot = chunk & 31;
    uint4 d = *(const uint4*)(qkv + (g0 + row) * NQKV + slot * 8);
    *(uint4*)(sm + row * 512 + ((slot ^ (row & 7)) << 4)) = d;
  }
  __syncthreads();

  f32x4 eacc[4] = {};
#pragma unroll
  for (int kk = 0; kk < 8; ++kk) {
    int ra = 16 * w + (l & 15);
    bf16x8 af = *(const bf16x8*)(sm + ra * 512 + (((kk * 4 + (l >> 4)) ^ (ra & 7)) << 4));
#pragma unroll
    for (int nj = 0; nj < 4; ++nj) {
      int rb = 16 * nj + (l & 15);
      bf16x8 bf_ = *(const bf16x8*)(sm + rb * 512 + (((kk * 4 + (l >> 4)) ^ (rb & 7)) << 4));
      eacc[nj] = __builtin_amdgcn_mfma_f32_16x16x32_bf16(af, bf_, eacc[nj], 0, 0, 0);
    }
  }
#pragma unroll
  for (int nj = 0; nj < 4; ++nj)
#pragma unroll
    for (int r = 0; r < 4; ++r) {
      int i = 16 * w + (l >> 4) * 4 + r;
      int j = 16 * nj + (l & 15);
      E[i * 65 + j] = eacc[nj][r] * 0.0625f;
    }
  __syncthreads();

  auto stage_v = [&](int h) {
#pragma unroll
    for (int ch = 0; ch < 8; ++ch) {
      int cb = w * 64 + ch * 8;
      B8 d; d.u = *(const uint4*)(qkv + (g0 + l) * NQKV + 256 + h * 256 + cb);
#pragma unroll
      for (int e = 0; e < 8; ++e) {
        int c = cb + e;
        *(__bf16*)(sm + c * 128 + (((l >> 3) ^ (c & 7)) << 4) + (l & 7) * 2) = d.h[e];
      }
    }
  };

  auto pv_half = [&](int h) {
    f32x4 acc[4][4] = {};
#pragma unroll
    for (int ks = 0; ks < 2; ++ks) {
      bf16x8 af[4];
#pragma unroll
      for (int mi = 0; mi < 4; ++mi) {
        int i = mi * 16 + (l & 15);
        float ri = rowinv[i];
        bf16x8 a;
#pragma unroll
        for (int e = 0; e < 8; ++e) {
          int j = ks * 32 + (l >> 4) * 8 + e;
          a[e] = (__bf16)(E[i * 65 + j] * colinv[j] * ri);
        }
        af[mi] = a;
      }
#pragma unroll
      for (int nc = 0; nc < 4; ++nc) {
        int c = w * 64 + nc * 16 + (l & 15);
        int slot = (ks * 4 + (l >> 4)) ^ (c & 7);
        bf16x8 bfr = *(const bf16x8*)(sm + c * 128 + (slot << 4));
#pragma unroll
        for (int mi = 0; mi < 4; ++mi)
          acc[mi][nc] = __builtin_amdgcn_mfma_f32_16x16x32_bf16(af[mi], bfr, acc[mi][nc], 0, 0, 0);
      }
    }
#pragma unroll
    for (int mi = 0; mi < 4; ++mi)
#pragma unroll
      for (int nc = 0; nc < 4; ++nc)
#pragma unroll
        for (int r = 0; r < 4; ++r) {
          int i = mi * 16 + (l >> 4) * 4 + r;
          int c = h * 256 + w * 64 + nc * 16 + (l & 15);
          size_t idx = (g0 + i) * CH + c;
          float av = (float)atom16[idx];
          xt[idx] = (__bf16)(av - acc[mi][nc][r]);
        }
  };

  stage_v(0);
  if (t < 64) {
    float m = -1e30f;
    for (int i = 0; i < 64; ++i) m = fmaxf(m, E[i * 65 + t]);
    float s = 0.f;
    for (int i = 0; i < 64; ++i) { float e = __expf(E[i * 65 + t] - m); E[i * 65 + t] = e; s += e; }
    colinv[t] = 1.f / s;
  }
  __syncthreads();
  if (t < 64) {
    float rs = 0.f;
    for (int j = 0; j < 64; ++j) rs += E[t * 65 + j] * colinv[j];
    rowinv[t] = 1.f / (1e-9f + rs);
  }
  __syncthreads();
  pv_half(0);
  __syncthreads();
  stage_v(1);
  __syncthreads();
  pv_half(1);
}

// ---------------- BN scale/shift from accumulated stats ----------------
__global__ void k_stats(const float* __restrict__ stats, const float* __restrict__ gamma,
                        const float* __restrict__ beta, float* __restrict__ ss)
{
  int c = threadIdx.x;
  float mean = stats[c] * (1.f / NAT);
  float var = stats[512 + c] * (1.f / NAT) - mean * mean;
  float sc = gamma[c] * rsqrtf(var + 1e-5f);
  ss[c] = sc;
  ss[512 + c] = beta[c] - mean * sc;
}

// ---------------- final: out = atom + relu(t*scale + shift) ----------------
__global__ void k_final(const float* __restrict__ atom, const __bf16* __restrict__ tmat,
                        const float* __restrict__ ss, float* __restrict__ out)
{
  int tid = blockIdx.x * blockDim.x + threadIdx.x;
  int nth = gridDim.x * blockDim.x;
  for (int i = tid; i < NAT * CH / 8; i += nth) {
    int colb = (i & 63) * 8;
    B8 tv; tv.u = ((const uint4*)tmat)[i];
    float4 a0 = ((const float4*)atom)[2 * i], a1 = ((const float4*)atom)[2 * i + 1];
    float4 s0 = *(const float4*)(ss + colb), s1 = *(const float4*)(ss + colb + 4);
    float4 h0 = *(const float4*)(ss + 512 + colb), h1 = *(const float4*)(ss + 512 + colb + 4);
    float4 o0, o1;
    o0.x = a0.x + fmaxf(0.f, (float)tv.h[0] * s0.x + h0.x);
    o0.y = a0.y + fmaxf(0.f, (float)tv.h[1] * s0.y + h0.y);
    o0.z = a0.z + fmaxf(0.f, (float)tv.h[2] * s0.z + h0.z);
    o0.w = a0.w + fmaxf(0.f, (float)tv.h[3] * s0.w + h0.w);
    o1.x = a1.x + fmaxf(0.f, (float)tv.h[4] * s1.x + h1.x);
    o1.y = a1.y + fmaxf(0.f, (float)tv.h[5] * s1.y + h1.y);
    o1.z = a1.z + fmaxf(0.f, (float)tv.h[6] * s1.z + h1.z);
    o1.w = a1.w + fmaxf(0.f, (float)tv.h[7] * s1.w + h1.w);
    ((float4*)out)[2 * i] = o0;
    ((float4*)out)[2 * i + 1] = o1;
  }
}

extern "C" void kernel_launch(void* const* d_in, const int* in_sizes, int n_in,
                              void* d_out, int out_size, void* d_ws, size_t ws_size,
                              hipStream_t stream) {
  const float* atom  = (const float*)d_in[0];
  const float* wqk   = (const float*)d_in[1];
  const float* bqk   = (const float*)d_in[2];
  const float* wv    = (const float*)d_in[3];
  const float* bv    = (const float*)d_in[4];
  const float* wt    = (const float*)d_in[5];
  const float* bt    = (const float*)d_in[6];
  const float* gamma = (const float*)d_in[7];
  const float* beta  = (const float*)d_in[8];
  char* ws = (char*)d_ws;

  // Region A [0, 64MB): atom16; attn reads atom16[idx] then writes xtr[idx] (same address,
  // per-element, one owner thread) -> safe in-place. atom16 is dead after attn.
  // Region B [64MB, 160MB): qkv (dead after attn) -> tmat
  __bf16* atom16 = (__bf16*)(ws);                    // 67,108,864 B
  __bf16* xtr    = (__bf16*)(ws);                    // in-place over atom16
  __bf16* qkv    = (__bf16*)(ws + 67108864);         // 100,663,296 B
  __bf16* tmat   = (__bf16*)(ws + 67108864);         // overlaps qkv (dead)
  __bf16* wqkv16 = (__bf16*)(ws + 167772160);        // 786,432 B
  __bf16* wt16   = (__bf16*)(ws + 168558592);        // 524,288 B
  float*  bqkv   = (float*)(ws + 169082880);         // 3,072 B
  float*  stats  = (float*)(ws + 169085952);         // 4,096 B
  float*  ss     = (float*)(ws + 169090048);         // 4,096 B
  float*  out    = (float*)d_out;

  k_prep<<<dim3(2048), dim3(256), 0, stream>>>(atom, wqk, bqk, wv, bv, wt,
                                               atom16, wqkv16, bqkv, wt16, stats);
  k_gemm<NQKV, false><<<dim3(512, 6), dim3(256), 0, stream>>>(atom16, wqkv16, bqkv, qkv, nullptr);
  k_attn<<<dim3(1024), dim3(256), 0, stream>>>(qkv, atom16, xtr);
  k_gemm<CH, true><<<dim3(512, 4), dim3(256), 0, stream>>>(xtr, wt16, bt, tmat, stats);
  k_stats<<<dim3(1), dim3(512), 0, stream>>>(stats, gamma, beta, ss);
  k_final<<<dim3(2048), dim3(256), 0, stream>>>(atom, tmat, ss, out);
}

// Round 4
// 476.033 us; speedup vs baseline: 1.1183x; 1.1124x over previous
//
#include <hip/hip_runtime.h>
#include <stdint.h>

#define NAT 65536
#define CH 512
#define NQKV 768

typedef __bf16 bf16x8 __attribute__((ext_vector_type(8)));
typedef float f32x4 __attribute__((ext_vector_type(4)));

union B8 { uint4 u; __bf16 h[8]; };

__device__ __forceinline__ void gload16(const void* g, void* l) {
  __builtin_amdgcn_global_load_lds((const __attribute__((address_space(1))) void*)g,
                                   (__attribute__((address_space(3))) void*)l, 16, 0, 0);
}

// ---------------- prep: fp32 -> bf16 conversions + stats zero ----------------
__global__ void k_prep(const float* __restrict__ atom, const float* __restrict__ wqk,
                       const float* __restrict__ bqk, const float* __restrict__ wv,
                       const float* __restrict__ bv, const float* __restrict__ wt,
                       __bf16* __restrict__ atom16, __bf16* __restrict__ wqkv16,
                       float* __restrict__ bqkv, __bf16* __restrict__ wt16,
                       float* __restrict__ stats)
{
  int tid = blockIdx.x * blockDim.x + threadIdx.x;
  int nth = gridDim.x * blockDim.x;
  const float4* a4 = (const float4*)atom;
  for (int i = tid; i < NAT * CH / 8; i += nth) {
    float4 x = a4[2 * i], y = a4[2 * i + 1];
    B8 u;
    u.h[0] = (__bf16)x.x; u.h[1] = (__bf16)x.y; u.h[2] = (__bf16)x.z; u.h[3] = (__bf16)x.w;
    u.h[4] = (__bf16)y.x; u.h[5] = (__bf16)y.y; u.h[6] = (__bf16)y.z; u.h[7] = (__bf16)y.w;
    ((uint4*)atom16)[i] = u.u;
  }
  for (int i = tid; i < NQKV * CH / 8; i += nth) {
    int row = (i * 8) >> 9;
    const float* src = (row < 256) ? (wqk + (size_t)i * 8) : (wv + (size_t)i * 8 - 256 * 512);
    float4 x = ((const float4*)src)[0], y = ((const float4*)src)[1];
    B8 u;
    u.h[0] = (__bf16)x.x; u.h[1] = (__bf16)x.y; u.h[2] = (__bf16)x.z; u.h[3] = (__bf16)x.w;
    u.h[4] = (__bf16)y.x; u.h[5] = (__bf16)y.y; u.h[6] = (__bf16)y.z; u.h[7] = (__bf16)y.w;
    ((uint4*)wqkv16)[i] = u.u;
  }
  for (int i = tid; i < CH * CH / 8; i += nth) {
    float4 x = ((const float4*)wt)[2 * i], y = ((const float4*)wt)[2 * i + 1];
    B8 u;
    u.h[0] = (__bf16)x.x; u.h[1] = (__bf16)x.y; u.h[2] = (__bf16)x.z; u.h[3] = (__bf16)x.w;
    u.h[4] = (__bf16)y.x; u.h[5] = (__bf16)y.y; u.h[6] = (__bf16)y.z; u.h[7] = (__bf16)y.w;
    ((uint4*)wt16)[i] = u.u;
  }
  if (tid < NQKV) bqkv[tid] = (tid < 256) ? bqk[tid] : bv[tid - 256];
  if (tid < 1024) stats[tid] = 0.f;
}

// ---------------- GEMM: C[M,NOUT] = A[M,512] @ W[NOUT,512]^T + bias ----------------
// 128x256 tile, BK=64, 8 waves (2x4 of 64x64), single 48KB LDS buffer,
// mfma 16x16x32 bf16. global_load_lds w/ pre-swizzled source + swizzled reads.
// Direct scalar C-stores (L2 write-merging verified exact WRITE_SIZE in r2).
template<int NOUT, bool STATS>
__global__ __launch_bounds__(512, 4) void k_gemm(const __bf16* __restrict__ A,
    const __bf16* __restrict__ W, const float* __restrict__ bias,
    __bf16* __restrict__ Cout, float* __restrict__ stats)
{
  __shared__ __align__(16) char lds[49152];   // A 16KB + B 32KB
  const int t = threadIdx.x, w = t >> 6, l = t & 63;
  const int wr = w >> 2, wc = w & 3;          // wave grid 2(M) x 4(N)
  const int m0 = blockIdx.x * 128, n0 = blockIdx.y * 256;
  const int lrow = l >> 3;                    // 0..7 (row within 8-row chunk)
  const int lslot = (l & 7) ^ lrow;           // pre-swizzled global 16B-slot
  f32x4 acc[4][4] = {};

  for (int kt = 0; kt < 8; ++kt) {
    const int k0 = kt * 64;
#pragma unroll
    for (int i = 0; i < 2; ++i) {             // A: 16 chunks of 1KB, 8 waves x 2
      int row = (i * 8 + w) * 8 + lrow;       // 0..127
      gload16(A + ((size_t)(m0 + row) * 512 + k0 + lslot * 8), lds + (i * 8 + w) * 1024);
    }
#pragma unroll
    for (int i = 0; i < 4; ++i) {             // B: 32 chunks, 8 waves x 4
      int row = (i * 8 + w) * 8 + lrow;       // 0..255
      gload16(W + ((size_t)(n0 + row) * 512 + k0 + lslot * 8), lds + 16384 + (i * 8 + w) * 1024);
    }
    asm volatile("s_waitcnt vmcnt(0)" ::: "memory");
    __syncthreads();
#pragma unroll
    for (int ks = 0; ks < 2; ++ks) {
      bf16x8 af[4];
#pragma unroll
      for (int mi = 0; mi < 4; ++mi) {
        int r = wr * 64 + mi * 16 + (l & 15);
        af[mi] = *(const bf16x8*)(lds + r * 128 + (((ks * 4 + (l >> 4)) ^ (r & 7)) << 4));
      }
#pragma unroll
      for (int ni = 0; ni < 4; ++ni) {
        int r = wc * 64 + ni * 16 + (l & 15);
        bf16x8 bfr = *(const bf16x8*)(lds + 16384 + r * 128 + (((ks * 4 + (l >> 4)) ^ (r & 7)) << 4));
#pragma unroll
        for (int mi = 0; mi < 4; ++mi)
          acc[mi][ni] = __builtin_amdgcn_mfma_f32_16x16x32_bf16(af[mi], bfr, acc[mi][ni], 0, 0, 0);
      }
    }
    __syncthreads();
  }

  // epilogue: bias (+stats), direct stores
  float ssum[4] = {0, 0, 0, 0}, ssq[4] = {0, 0, 0, 0};
#pragma unroll
  for (int ni = 0; ni < 4; ++ni) {
    int col = n0 + wc * 64 + ni * 16 + (l & 15);
    float bb = bias[col];
#pragma unroll
    for (int mi = 0; mi < 4; ++mi) {
#pragma unroll
      for (int r = 0; r < 4; ++r) {
        int row = m0 + wr * 64 + mi * 16 + (l >> 4) * 4 + r;
        float v = acc[mi][ni][r] + bb;
        Cout[(size_t)row * NOUT + col] = (__bf16)v;
        if (STATS) { ssum[ni] += v; ssq[ni] += v * v; }
      }
    }
  }
  if (STATS) {
#pragma unroll
    for (int ni = 0; ni < 4; ++ni) {
      float s = ssum[ni], q = ssq[ni];
      s += __shfl_xor(s, 16, 64); q += __shfl_xor(q, 16, 64);
      s += __shfl_xor(s, 32, 64); q += __shfl_xor(q, 32, 64);
      if (l < 16) {
        int col = n0 + wc * 64 + ni * 16 + l;
        atomicAdd(&stats[col], s);
        atomicAdd(&stats[512 + col], q);
      }
    }
  }
}

// ---------------- per-crystal attention ----------------
// One block per crystal (64 atoms). energy = qk qk^T/16; softmax over query axis i
// (wave-parallel, 4-lane quads per column); L1 over keys j; x_r = att @ v;
// xt = atom16 - x_r via LDS-bounced vectorized epilogue.
__global__ __launch_bounds__(256, 2) void k_attn(const __bf16* __restrict__ qkv,
    const __bf16* __restrict__ atom16, __bf16* __restrict__ xt)
{
  __shared__ __align__(16) char sm[49920];
  // region0 [0,32768): qk [64][256]bf16 swz -> V half [256][64]bf16 swz -> out half [64][256]bf16 swz
  float* E = (float*)(sm + 32768);         // [64][65] f32 (padded)
  float* colinv = (float*)(sm + 49408);    // [64]
  float* rowinv = (float*)(sm + 49664);    // [64]
  const int t = threadIdx.x, w = t >> 6, l = t & 63;
  const size_t g0 = (size_t)blockIdx.x * 64;

  // stage qk [64][256], XOR-swizzled 16B slots
#pragma unroll
  for (int i = 0; i < 8; ++i) {
    int chunk = i * 256 + t;
    int row = chunk >> 5, slot = chunk & 31;
    uint4 d = *(const uint4*)(qkv + (g0 + row) * NQKV + slot * 8);
    *(uint4*)(sm + row * 512 + ((slot ^ (row & 7)) << 4)) = d;
  }
  __syncthreads();

  // energy: wave w computes rows [16w, 16w+16)
  f32x4 eacc[4] = {};
#pragma unroll
  for (int kk = 0; kk < 8; ++kk) {
    int ra = 16 * w + (l & 15);
    bf16x8 af = *(const bf16x8*)(sm + ra * 512 + (((kk * 4 + (l >> 4)) ^ (ra & 7)) << 4));
#pragma unroll
    for (int nj = 0; nj < 4; ++nj) {
      int rb = 16 * nj + (l & 15);
      bf16x8 bf_ = *(const bf16x8*)(sm + rb * 512 + (((kk * 4 + (l >> 4)) ^ (rb & 7)) << 4));
      eacc[nj] = __builtin_amdgcn_mfma_f32_16x16x32_bf16(af, bf_, eacc[nj], 0, 0, 0);
    }
  }
#pragma unroll
  for (int nj = 0; nj < 4; ++nj)
#pragma unroll
    for (int r = 0; r < 4; ++r) {
      int i = 16 * w + (l >> 4) * 4 + r;
      int j = 16 * nj + (l & 15);
      E[i * 65 + j] = eacc[nj][r] * 0.0625f;   // / sqrt(dk)=16
    }
  __syncthreads();

  // stage V half h as v_t[c][j] swizzled; lane l owns atom row j=l
  auto stage_v = [&](int h) {
#pragma unroll
    for (int ch = 0; ch < 8; ++ch) {
      int cb = w * 64 + ch * 8;
      B8 d; d.u = *(const uint4*)(qkv + (g0 + l) * NQKV + 256 + h * 256 + cb);
#pragma unroll
      for (int e = 0; e < 8; ++e) {
        int c = cb + e;
        *(__bf16*)(sm + c * 128 + (((l >> 3) ^ (c & 7)) << 4) + (l & 7) * 2) = d.h[e];
      }
    }
  };

  stage_v(0);   // overlaps with softmax phases (region0 not read until PV)

  // phase A: softmax over query axis i, per column j; 4-lane quad per column
  {
    int j = t >> 2, sub = t & 3;
    float m = -1e30f;
#pragma unroll
    for (int k = 0; k < 16; ++k) m = fmaxf(m, E[(sub + 4 * k) * 65 + j]);
    m = fmaxf(m, __shfl_xor(m, 1)); m = fmaxf(m, __shfl_xor(m, 2));
    float s = 0.f;
#pragma unroll
    for (int k = 0; k < 16; ++k) {
      float e = __expf(E[(sub + 4 * k) * 65 + j] - m);
      E[(sub + 4 * k) * 65 + j] = e; s += e;
    }
    s += __shfl_xor(s, 1); s += __shfl_xor(s, 2);
    if (sub == 0) colinv[j] = 1.f / s;
  }
  __syncthreads();
  // phase B: L1 over keys j, per row i
  {
    int i = t >> 2, sub = t & 3;
    float rs = 0.f;
#pragma unroll
    for (int k = 0; k < 16; ++k) { int j = sub + 4 * k; rs += E[i * 65 + j] * colinv[j]; }
    rs += __shfl_xor(rs, 1); rs += __shfl_xor(rs, 2);
    if (sub == 0) rowinv[i] = 1.f / (1e-9f + rs);
  }
  __syncthreads();

  // PV for half h + vectorized epilogue (xt = atom16 - x_r)
  auto pv_out = [&](int h) {
    f32x4 acc[4][4] = {};
#pragma unroll
    for (int ks = 0; ks < 2; ++ks) {
      bf16x8 af[4];
#pragma unroll
      for (int mi = 0; mi < 4; ++mi) {
        int i = mi * 16 + (l & 15);
        float ri = rowinv[i];
        bf16x8 a;
#pragma unroll
        for (int e = 0; e < 8; ++e) {
          int j = ks * 32 + (l >> 4) * 8 + e;
          a[e] = (__bf16)(E[i * 65 + j] * colinv[j] * ri);
        }
        af[mi] = a;
      }
#pragma unroll
      for (int nc = 0; nc < 4; ++nc) {
        int c = w * 64 + nc * 16 + (l & 15);
        bf16x8 bfr = *(const bf16x8*)(sm + c * 128 + (((ks * 4 + (l >> 4)) ^ (c & 7)) << 4));
#pragma unroll
        for (int mi = 0; mi < 4; ++mi)
          acc[mi][nc] = __builtin_amdgcn_mfma_f32_16x16x32_bf16(af[mi], bfr, acc[mi][nc], 0, 0, 0);
      }
    }
    __syncthreads();                 // all waves done reading V-half from region0
    // scatter x_r to region0 as [64][256] bf16, XOR-swizzled 16B slots
#pragma unroll
    for (int mi = 0; mi < 4; ++mi)
#pragma unroll
      for (int nc = 0; nc < 4; ++nc)
#pragma unroll
        for (int r = 0; r < 4; ++r) {
          int i = mi * 16 + (l >> 4) * 4 + r;
          int c = w * 64 + nc * 16 + (l & 15);
          int s = c >> 3;
          *(__bf16*)(sm + i * 512 + (((s ^ (i & 7))) << 4) + (c & 7) * 2) = (__bf16)acc[mi][nc][r];
        }
    __syncthreads();
    // vectorized out: 16B loads of atom16 / stores of xt
#pragma unroll
    for (int j = 0; j < 8; ++j) {
      int chunk = j * 256 + t;
      int row = chunk >> 5, p = chunk & 31;
      int s = p ^ (row & 7);
      B8 xv; xv.u = *(const uint4*)(sm + row * 512 + p * 16);
      B8 av; av.u = *(const uint4*)(atom16 + (g0 + row) * 512 + h * 256 + s * 8);
      B8 o;
#pragma unroll
      for (int e = 0; e < 8; ++e) o.h[e] = (__bf16)((float)av.h[e] - (float)xv.h[e]);
      *(uint4*)(xt + (g0 + row) * 512 + h * 256 + s * 8) = o.u;
    }
  };

  pv_out(0);
  __syncthreads();   // before stage_v(1) overwrites region0
  stage_v(1);
  __syncthreads();
  pv_out(1);
}

// ---------------- BN scale/shift from accumulated stats ----------------
__global__ void k_stats(const float* __restrict__ stats, const float* __restrict__ gamma,
                        const float* __restrict__ beta, float* __restrict__ ss)
{
  int c = threadIdx.x;
  float mean = stats[c] * (1.f / NAT);
  float var = stats[512 + c] * (1.f / NAT) - mean * mean;
  float sc = gamma[c] * rsqrtf(var + 1e-5f);
  ss[c] = sc;
  ss[512 + c] = beta[c] - mean * sc;
}

// ---------------- final: out = atom + relu(t*scale + shift) ----------------
__global__ void k_final(const float* __restrict__ atom, const __bf16* __restrict__ tmat,
                        const float* __restrict__ ss, float* __restrict__ out)
{
  int tid = blockIdx.x * blockDim.x + threadIdx.x;
  int nth = gridDim.x * blockDim.x;
  for (int i = tid; i < NAT * CH / 8; i += nth) {
    int colb = (i & 63) * 8;
    B8 tv; tv.u = ((const uint4*)tmat)[i];
    float4 a0 = ((const float4*)atom)[2 * i], a1 = ((const float4*)atom)[2 * i + 1];
    float4 s0 = *(const float4*)(ss + colb), s1 = *(const float4*)(ss + colb + 4);
    float4 h0 = *(const float4*)(ss + 512 + colb), h1 = *(const float4*)(ss + 512 + colb + 4);
    float4 o0, o1;
    o0.x = a0.x + fmaxf(0.f, (float)tv.h[0] * s0.x + h0.x);
    o0.y = a0.y + fmaxf(0.f, (float)tv.h[1] * s0.y + h0.y);
    o0.z = a0.z + fmaxf(0.f, (float)tv.h[2] * s0.z + h0.z);
    o0.w = a0.w + fmaxf(0.f, (float)tv.h[3] * s0.w + h0.w);
    o1.x = a1.x + fmaxf(0.f, (float)tv.h[4] * s1.x + h1.x);
    o1.y = a1.y + fmaxf(0.f, (float)tv.h[5] * s1.y + h1.y);
    o1.z = a1.z + fmaxf(0.f, (float)tv.h[6] * s1.z + h1.z);
    o1.w = a1.w + fmaxf(0.f, (float)tv.h[7] * s1.w + h1.w);
    ((float4*)out)[2 * i] = o0;
    ((float4*)out)[2 * i + 1] = o1;
  }
}

extern "C" void kernel_launch(void* const* d_in, const int* in_sizes, int n_in,
                              void* d_out, int out_size, void* d_ws, size_t ws_size,
                              hipStream_t stream) {
  const float* atom  = (const float*)d_in[0];
  const float* wqk   = (const float*)d_in[1];
  const float* bqk   = (const float*)d_in[2];
  const float* wv    = (const float*)d_in[3];
  const float* bv    = (const float*)d_in[4];
  const float* wt    = (const float*)d_in[5];
  const float* bt    = (const float*)d_in[6];
  const float* gamma = (const float*)d_in[7];
  const float* beta  = (const float*)d_in[8];
  char* ws = (char*)d_ws;

  // Region A [0, 64MB): atom16; attn reads atom16[idx] then writes xt[idx] (same thread,
  // same address, read-before-write) -> safe in-place. atom16 dead after attn.
  // Region B [64MB, 160MB): qkv (dead after attn) -> tmat
  __bf16* atom16 = (__bf16*)(ws);                    // 67,108,864 B
  __bf16* xtr    = (__bf16*)(ws);                    // in-place over atom16
  __bf16* qkv    = (__bf16*)(ws + 67108864);         // 100,663,296 B
  __bf16* tmat   = (__bf16*)(ws + 67108864);         // overlaps qkv (dead)
  __bf16* wqkv16 = (__bf16*)(ws + 167772160);        // 786,432 B
  __bf16* wt16   = (__bf16*)(ws + 168558592);        // 524,288 B
  float*  bqkv   = (float*)(ws + 169082880);         // 3,072 B
  float*  stats  = (float*)(ws + 169085952);         // 4,096 B
  float*  ss     = (float*)(ws + 169090048);         // 4,096 B
  float*  out    = (float*)d_out;

  k_prep<<<dim3(2048), dim3(256), 0, stream>>>(atom, wqk, bqk, wv, bv, wt,
                                               atom16, wqkv16, bqkv, wt16, stats);
  k_gemm<NQKV, false><<<dim3(512, 3), dim3(512), 0, stream>>>(atom16, wqkv16, bqkv, qkv, nullptr);
  k_attn<<<dim3(1024), dim3(256), 0, stream>>>(qkv, atom16, xtr);
  k_gemm<CH, true><<<dim3(512, 2), dim3(512), 0, stream>>>(xtr, wt16, bt, tmat, stats);
  k_stats<<<dim3(1), dim3(512), 0, stream>>>(stats, gamma, beta, ss);
  k_final<<<dim3(2048), dim3(256), 0, stream>>>(atom, tmat, ss, out);
}